// Round 17
// baseline (77.117 us; speedup 1.0000x reference)
//
#include <hip/hip_runtime.h>
#include <hip/hip_bf16.h>
#include <math.h>

// Problem constants (match reference)
#define B_ 16
#define L_ 256
#define A_ 128
#define D_ 4
#define H_ 64
#define DFF_ 256
#define PRED_ 64
#define COUT_ 8

// ws layout (floats)
// gate weights SoA, exp2-prescaled: [g][d][64], g=0:z (x L2E), g=1:h (x 2*L2E)
#define WS_GW   0
// gate biases, same prescale: [g][64]
#define WS_GB   512
#define WS_PART 640                       // [B*L][64] per-(b,l) agent-sums

#define L2E 1.4426950408889634f

typedef float v2 __attribute__((ext_vector_type(2)));

// bf16 helpers: pack two f32 -> u32 (RTN-even), unpack u32 -> two f32.
__device__ inline unsigned pk_bf16(float a, float b)
{
    unsigned ua = __builtin_bit_cast(unsigned, a);
    unsigned ub = __builtin_bit_cast(unsigned, b);
    ua = (ua + 0x7fffu + ((ua >> 16) & 1u)) >> 16;
    ub = (ub + 0x7fffu + ((ub >> 16) & 1u)) >> 16;
    return ua | (ub << 16);
}
__device__ inline float bl16lo(unsigned u)
{
    return __builtin_bit_cast(float, u << 16);
}
__device__ inline float bl16hi(unsigned u)
{
    return __builtin_bit_cast(float, u & 0xffff0000u);
}

// ---------------------------------------------------------------------------
// Kernel 0: fold gate weights, PARALLEL: 5 blocks x 128 threads, one output
// per thread. Wg' = (W_g @ Lg_w[0:64,:]) * s_g stored SoA [d][j]; bg'
// likewise. s_z = log2(e), s_h = 2*log2(e). R gate is dead code: dropped.
// ---------------------------------------------------------------------------
__global__ __launch_bounds__(128) void precomp_kernel(
    const float* __restrict__ W_z, const float* __restrict__ b_z,
    const float* __restrict__ W_h, const float* __restrict__ b_h,
    const float* __restrict__ Lz_w, const float* __restrict__ Lz_b,
    const float* __restrict__ Lh_w, const float* __restrict__ Lh_b,
    float* __restrict__ ws)
{
    const int idx = blockIdx.x * 128 + threadIdx.x;   // 0..639
    if (idx < 512) {
        const int g = idx >> 8;
        const int d = (idx >> 6) & 3;
        const int j = idx & 63;
        const float* W  = g ? W_h  : W_z;
        const float* Lw = g ? Lh_w : Lz_w;
        float acc = 0.f;
        #pragma unroll 8
        for (int h = 0; h < 64; ++h)
            acc += W[d * 64 + h] * Lw[h * 64 + j];
        ws[WS_GW + g * 256 + d * 64 + j] = acc * (g ? 2.f * L2E : L2E);
    } else {
        const int i = idx - 512;           // 0..127
        const int g = i >> 6;
        const int j = i & 63;
        const float* bg = g ? b_h  : b_z;
        const float* Lw = g ? Lh_w : Lz_w;
        const float* Lb = g ? Lh_b : Lz_b;
        float acc = Lb[j];
        #pragma unroll 8
        for (int h = 0; h < 64; ++h)
            acc += bg[h] * Lw[h * 64 + j];
        ws[WS_GB + g * 64 + j] = acc * (g ? 2.f * L2E : L2E);
    }
}

// ---------------------------------------------------------------------------
// Kernel 1: round-16 structure + bf16 pair-packing of the DERIVED arrays.
// 512 threads per (b,l); 4 threads per agent-row; thread (r,q) owns columns
// e in {8k+2q, 8k+2q+1}. Pass 1 reads f32 xr (exact-zero diagonal -> w=1e6
// exact); 32 pairwise weights cached in named registers. xs = dinv*x and M
// are stored as bf16 PAIRS (uint4 = 2 agents), so pass 2 needs 16 reads and
// gates 8 reads (DS total 80 -> 56 instrs/thread; the r16 kernel sat at
// 102% of the DS-issue roofline, so fewer DS instructions is the only lever).
// bf16 error enters only via xs/M (<=0.2% of m) -> final out err ~1e-5,
// 200x under threshold. (512,6): r16-proven no-spill for this cache size.
// ---------------------------------------------------------------------------
#define REP16(M) M(0) M(1) M(2) M(3) M(4) M(5) M(6) M(7) \
                 M(8) M(9) M(10) M(11) M(12) M(13) M(14) M(15)

__global__ __launch_bounds__(512, 6) void tgcn_kernel(
    const float* __restrict__ x,
    const float* __restrict__ ws_w,
    float* __restrict__ part)
{
    __shared__ float4 xr4_s[128];     // agent features (f32)
    __shared__ uint4  xsb_s[64];      // bf16 pairs: dinv[e]*xr[e], 2 agents/entry
    __shared__ uint4  Mb_s[64];       // bf16 pairs: per-row m, 2 agents/entry
    __shared__ float  gw_s[512];      // [g][d][64] prescaled gate weights
    __shared__ float  gb_s[128];      // [g][64] prescaled gate biases
    __shared__ float  red_s[8][64];

    uint2* xsb2_s = (uint2*)xsb_s;    // per-row write view
    uint2* Mb2_s  = (uint2*)Mb_s;

    const int t  = threadIdx.x;
    const int bl = blockIdx.x;

    // ---- stage ----
    if (t < 128) {
        xr4_s[t] = ((const float4*)(x + (size_t)bl * (A_ * D_)))[t];
    } else if (t < 384) {
        int i = t - 128;
        gw_s[i]       = ws_w[WS_GW + i];
        gw_s[i + 256] = ws_w[WS_GW + i + 256];
    } else {
        gb_s[t - 384] = ws_w[WS_GB + (t - 384)];
    }
    __syncthreads();

    const int r = t >> 2;           // agent row 0..127
    const int q = t & 3;            // column-quarter; cols {8k+2q, 8k+2q+1}

    const float4 xa = xr4_s[r];
    const v2 xa01 = {xa.x, xa.y};
    const v2 xa23 = {xa.z, xa.w};

    // ---- pass 1: pairwise weights (f32, exact diag) -> named regs ----
#define DECLW(i) float wa##i; float wb##i;
    REP16(DECLW)
#undef DECLW
    float rs0 = 0.f, rs1 = 0.f;
#define PASS1P(i) { \
        float4 xe0 = xr4_s[8 * (i) + 2 * q]; \
        float4 xe1 = xr4_s[8 * (i) + 2 * q + 1]; \
        v2 dA = xa01 - (v2){xe0.x, xe0.y}; \
        v2 dB = xa23 - (v2){xe0.z, xe0.w}; \
        v2 s2 = dA * dA; \
        s2 = __builtin_elementwise_fma(dB, dB, s2); \
        wa##i = fminf(__builtin_amdgcn_rsqf(s2.x + s2.y), 1.0e6f); \
        v2 dC = xa01 - (v2){xe1.x, xe1.y}; \
        v2 dD = xa23 - (v2){xe1.z, xe1.w}; \
        v2 s3 = dC * dC; \
        s3 = __builtin_elementwise_fma(dD, dD, s3); \
        wb##i = fminf(__builtin_amdgcn_rsqf(s3.x + s3.y), 1.0e6f); \
        rs0 += wa##i; \
        rs1 += wb##i; }
    REP16(PASS1P)
#undef PASS1P
    float rs = rs0 + rs1;
    rs += __shfl_xor(rs, 1);
    rs += __shfl_xor(rs, 2);                   // all 4 lanes have full rowsum
    const float dinv = __builtin_amdgcn_rsqf(rs);
    if (q == 0) {
        xsb2_s[r] = make_uint2(pk_bf16(dinv * xa.x, dinv * xa.y),
                               pk_bf16(dinv * xa.z, dinv * xa.w));
    }
    __syncthreads();

    // ---- pass 2: m = w_row . xs, bf16 pair reads (16 instrs) ----
    v2 mA = {0.f, 0.f};
    v2 mB = {0.f, 0.f};
#define PASS2P(i) { \
        uint4 uv = xsb_s[4 * (i) + q]; \
        v2 wA2 = {wa##i, wa##i}; \
        v2 wB2 = {wb##i, wb##i}; \
        mA = __builtin_elementwise_fma(wA2, (v2){bl16lo(uv.x), bl16hi(uv.x)}, mA); \
        mB = __builtin_elementwise_fma(wA2, (v2){bl16lo(uv.y), bl16hi(uv.y)}, mB); \
        mA = __builtin_elementwise_fma(wB2, (v2){bl16lo(uv.z), bl16hi(uv.z)}, mA); \
        mB = __builtin_elementwise_fma(wB2, (v2){bl16lo(uv.w), bl16hi(uv.w)}, mB); }
    REP16(PASS2P)
#undef PASS2P
    float m0 = mA.x, m1 = mA.y, m2 = mB.x, m3 = mB.y;
    m0 += __shfl_xor(m0, 1); m0 += __shfl_xor(m0, 2);
    m1 += __shfl_xor(m1, 1); m1 += __shfl_xor(m1, 2);
    m2 += __shfl_xor(m2, 1); m2 += __shfl_xor(m2, 2);
    m3 += __shfl_xor(m3, 1); m3 += __shfl_xor(m3, 2);
    if (q == 0) {
        Mb2_s[r] = make_uint2(pk_bf16(dinv * m0, dinv * m1),
                              pk_bf16(dinv * m2, dinv * m3));
    }
    __syncthreads();

    // ---- gates: thread <-> column j; 16 agents per wave, 8 pair-reads ----
    {
        const int j  = t & 63;
        const int g  = t >> 6;                 // wave id 0..7 -> agent group
        const v2 W0 = {gw_s[j],       gw_s[256 + j]};
        const v2 W1 = {gw_s[64 + j],  gw_s[320 + j]};
        const v2 W2 = {gw_s[128 + j], gw_s[384 + j]};
        const v2 W3 = {gw_s[192 + j], gw_s[448 + j]};
        const v2 Bzh = {gb_s[j], gb_s[64 + j]};
        float acc = 0.f;
        #pragma unroll
        for (int i = 0; i < 8; ++i) {
            uint4 uv = Mb_s[g * 8 + i];        // wave-uniform broadcast
            // agent 2i
            {
                float q0 = bl16lo(uv.x);
                float q1 = bl16hi(uv.x);
                float q2 = bl16lo(uv.y);
                float q3 = bl16hi(uv.y);
                v2 zh = __builtin_elementwise_fma((v2){q0, q0}, W0, Bzh);
                zh = __builtin_elementwise_fma((v2){q1, q1}, W1, zh);
                zh = __builtin_elementwise_fma((v2){q2, q2}, W2, zh);
                zh = __builtin_elementwise_fma((v2){q3, q3}, W3, zh);
                float ez = __builtin_amdgcn_exp2f(zh.x);
                float e2 = __builtin_amdgcn_exp2f(zh.y);
                float num = e2 - 1.f;
                float den = (1.f + ez) * (1.f + e2);
                acc += fmaxf(num * __builtin_amdgcn_rcpf(den), 0.f);
            }
            // agent 2i+1
            {
                float q0 = bl16lo(uv.z);
                float q1 = bl16hi(uv.z);
                float q2 = bl16lo(uv.w);
                float q3 = bl16hi(uv.w);
                v2 zh = __builtin_elementwise_fma((v2){q0, q0}, W0, Bzh);
                zh = __builtin_elementwise_fma((v2){q1, q1}, W1, zh);
                zh = __builtin_elementwise_fma((v2){q2, q2}, W2, zh);
                zh = __builtin_elementwise_fma((v2){q3, q3}, W3, zh);
                float ez = __builtin_amdgcn_exp2f(zh.x);
                float e2 = __builtin_amdgcn_exp2f(zh.y);
                float num = e2 - 1.f;
                float den = (1.f + ez) * (1.f + e2);
                acc += fmaxf(num * __builtin_amdgcn_rcpf(den), 0.f);
            }
        }
        red_s[g][j] = acc;
    }
    __syncthreads();

    if (t < 64) {
        float s = red_s[0][t] + red_s[1][t] + red_s[2][t] + red_s[3][t]
                + red_s[4][t] + red_s[5][t] + red_s[6][t] + red_s[7][t];
        part[(size_t)bl * 64 + t] = s;
    }
}

// ---------------------------------------------------------------------------
// Kernel 2: fused pool + decoder. One block of 1024 threads per batch.
// ---------------------------------------------------------------------------
__global__ __launch_bounds__(1024) void pooldec_kernel(
    const float* __restrict__ part,
    const float* __restrict__ D1_w, const float* __restrict__ D1_b,
    const float* __restrict__ D2_w, const float* __restrict__ D2_b,
    float* __restrict__ out)
{
    __shared__ float red_s[16][64];
    __shared__ float pooled_s[64];
    __shared__ float t1_s[256];
    const int t = threadIdx.x, b = blockIdx.x;

    // ---- pool over L: 16 groups x 16 rows ----
    {
        const int j = t & 63, g = t >> 6;
        const float* pb = part + ((size_t)b * L_ + g * 16) * 64;
        float s = 0.f;
        #pragma unroll
        for (int i = 0; i < 16; ++i) s += pb[i * 64 + j];
        red_s[g][j] = s;
    }
    __syncthreads();
    if (t < 64) {
        float s = 0.f;
        #pragma unroll
        for (int g = 0; g < 16; ++g) s += red_s[g][t];
        pooled_s[t] = s * (1.f / ((float)L_ * (float)A_));
    }
    __syncthreads();

    // ---- D1: 256 outputs, 4 threads per output (16 h each) ----
    {
        const int o = t >> 2, sub = t & 3;
        float acc = 0.f;
        #pragma unroll
        for (int hh = 0; hh < 16; ++hh) {
            int h = sub * 16 + hh;
            acc += pooled_s[h] * D1_w[h * 256 + o];
        }
        acc += __shfl_xor(acc, 1);
        acc += __shfl_xor(acc, 2);
        if (sub == 0) t1_s[o] = fmaxf(acc + D1_b[o], 0.f);
    }
    __syncthreads();

    // ---- D2: 512 outputs, 2 threads per output (128 k each) ----
    {
        const int o = t >> 1, kh = t & 1;
        float acc = 0.f;
        for (int kk = 0; kk < 128; ++kk) {
            int k = kh * 128 + kk;
            acc += t1_s[k] * D2_w[k * 512 + o];
        }
        acc += __shfl_xor(acc, 1);
        if (kh == 0) out[(size_t)b * 512 + o] = acc + D2_b[o];
    }
}

// ---------------------------------------------------------------------------
extern "C" void kernel_launch(void* const* d_in, const int* in_sizes, int n_in,
                              void* d_out, int out_size, void* d_ws, size_t ws_size,
                              hipStream_t stream)
{
    const float* x    = (const float*)d_in[0];
    // d_in[1..3]: x_mark_enc, x_dec, x_mark_dec — unused by the reference
    const float* W_z  = (const float*)d_in[4];
    const float* b_z  = (const float*)d_in[5];
    // d_in[6], d_in[7]: W_r, b_r — dead code in the reference
    const float* W_h  = (const float*)d_in[8];
    const float* b_h  = (const float*)d_in[9];
    const float* Lz_w = (const float*)d_in[10];
    const float* Lz_b = (const float*)d_in[11];
    // d_in[12], d_in[13]: Lr_w, Lr_b — dead
    const float* Lh_w = (const float*)d_in[14];
    const float* Lh_b = (const float*)d_in[15];
    const float* D1_w = (const float*)d_in[16];
    const float* D1_b = (const float*)d_in[17];
    const float* D2_w = (const float*)d_in[18];
    const float* D2_b = (const float*)d_in[19];

    float* ws  = (float*)d_ws;
    float* out = (float*)d_out;

    precomp_kernel<<<5, 128, 0, stream>>>(W_z, b_z, W_h, b_h,
                                          Lz_w, Lz_b, Lh_w, Lh_b, ws);
    tgcn_kernel<<<B_ * L_, 512, 0, stream>>>(x, ws, ws + WS_PART);
    pooldec_kernel<<<B_, 1024, 0, stream>>>(ws + WS_PART, D1_w, D1_b,
                                            D2_w, D2_b, out);
}

// Round 18
// 69.734 us; speedup vs baseline: 1.1059x; 1.1059x over previous
//
#include <hip/hip_runtime.h>
#include <hip/hip_bf16.h>
#include <math.h>

// Problem constants (match reference)
#define B_ 16
#define L_ 256
#define A_ 128
#define D_ 4
#define H_ 64
#define DFF_ 256
#define PRED_ 64
#define COUT_ 8

// ws layout (floats)
// gate weights SoA, exp2-prescaled: [g][d][64], g=0:z (x L2E), g=1:h (x 2*L2E)
#define WS_GW   0
// gate biases, same prescale: [g][64]
#define WS_GB   512
#define WS_PART 640                       // [B*L][64] per-(b,l) agent-sums

#define L2E 1.4426950408889634f

typedef float v2 __attribute__((ext_vector_type(2)));

// ---------------------------------------------------------------------------
// Kernel 0: fold gate weights, PARALLEL: 5 blocks x 128 threads, one output
// per thread. Wg' = (W_g @ Lg_w[0:64,:]) * s_g stored SoA [d][j]; bg'
// likewise. s_z = log2(e), s_h = 2*log2(e). R gate is dead code: dropped.
// ---------------------------------------------------------------------------
__global__ __launch_bounds__(128) void precomp_kernel(
    const float* __restrict__ W_z, const float* __restrict__ b_z,
    const float* __restrict__ W_h, const float* __restrict__ b_h,
    const float* __restrict__ Lz_w, const float* __restrict__ Lz_b,
    const float* __restrict__ Lh_w, const float* __restrict__ Lh_b,
    float* __restrict__ ws)
{
    const int idx = blockIdx.x * 128 + threadIdx.x;   // 0..639
    if (idx < 512) {
        const int g = idx >> 8;
        const int d = (idx >> 6) & 3;
        const int j = idx & 63;
        const float* W  = g ? W_h  : W_z;
        const float* Lw = g ? Lh_w : Lz_w;
        float acc = 0.f;
        #pragma unroll 8
        for (int h = 0; h < 64; ++h)
            acc += W[d * 64 + h] * Lw[h * 64 + j];
        ws[WS_GW + g * 256 + d * 64 + j] = acc * (g ? 2.f * L2E : L2E);
    } else {
        const int i = idx - 512;           // 0..127
        const int g = i >> 6;
        const int j = i & 63;
        const float* bg = g ? b_h  : b_z;
        const float* Lw = g ? Lh_w : Lz_w;
        const float* Lb = g ? Lh_b : Lz_b;
        float acc = Lb[j];
        #pragma unroll 8
        for (int h = 0; h < 64; ++h)
            acc += bg[h] * Lw[h * 64 + j];
        ws[WS_GB + g * 64 + j] = acc * (g ? 2.f * L2E : L2E);
    }
}

// ---------------------------------------------------------------------------
// Kernel 1 (round-16 configuration, the measured optimum of this family):
// one block of 512 threads per (b,l); 4 threads per agent-row, interleaved
// columns e = 4k+q (conflict-free LDS reads). The 32 pairwise weights are
// computed once (pass 1), cached in 32 NAMED registers (macro SSA), reused
// in pass 2. v2-packed FMA chains (VOP3P). (512,6) -> VGPR 40, no spill,
// ~53% occupancy; sits on the DS-issue roofline (80 ds_read_b128 x 12 cyc
// x 128 waves/CU = 123K cyc = 51 us), VALU ~70% overlapped.
// Measured session-wide alternatives, ALL worse: 2-row/256thr = 51
// (occupancy stall), 2-row recompute = 75 (VALU-bound), 2-row 8thr/row = 58
// (dep-bound), 64-reg cache = spill (90-280 MB scratch), bf16-packed
// xs/M = 59.6 (VALU-bound: unpack + doubled fma chains). Saddle point.
// ---------------------------------------------------------------------------
#define REP32(M) M(0) M(1) M(2) M(3) M(4) M(5) M(6) M(7) \
                 M(8) M(9) M(10) M(11) M(12) M(13) M(14) M(15) \
                 M(16) M(17) M(18) M(19) M(20) M(21) M(22) M(23) \
                 M(24) M(25) M(26) M(27) M(28) M(29) M(30) M(31)

__global__ __launch_bounds__(512, 6) void tgcn_kernel(
    const float* __restrict__ x,
    const float* __restrict__ ws_w,
    float* __restrict__ part)
{
    __shared__ float4 xr4_s[128];     // agent features
    __shared__ float4 xs4_s[128];     // dinv[e]*xr[e]
    __shared__ float4 M4_s[128];      // per-row m (pre-scaled by dinv[r])
    __shared__ float  gw_s[512];      // [g][d][64] prescaled gate weights
    __shared__ float  gb_s[128];      // [g][64] prescaled gate biases
    __shared__ float  red_s[8][64];

    const int t  = threadIdx.x;
    const int bl = blockIdx.x;

    // ---- stage ----
    if (t < 128) {
        xr4_s[t] = ((const float4*)(x + (size_t)bl * (A_ * D_)))[t];
    } else if (t < 384) {
        int i = t - 128;
        gw_s[i]       = ws_w[WS_GW + i];
        gw_s[i + 256] = ws_w[WS_GW + i + 256];
    } else {
        gb_s[t - 384] = ws_w[WS_GB + (t - 384)];
    }
    __syncthreads();

    const int r = t >> 2;           // agent row 0..127
    const int q = t & 3;            // column-quarter (interleaved)

    const float4 xa = xr4_s[r];
    const v2 xa01 = {xa.x, xa.y};
    const v2 xa23 = {xa.z, xa.w};

    // ---- pass 1: pairwise weights -> named regs + rowsum ----
#define DECLW(i) float w##i;
    REP32(DECLW)
#undef DECLW
    float rs0 = 0.f, rs1 = 0.f;
#define PASS1(i) { \
        float4 xe = xr4_s[((i) << 2) | q]; \
        v2 d01 = xa01 - (v2){xe.x, xe.y}; \
        v2 d23 = xa23 - (v2){xe.z, xe.w}; \
        v2 s2 = d01 * d01; \
        s2 = __builtin_elementwise_fma(d23, d23, s2); \
        float d2 = s2.x + s2.y; \
        w##i = fminf(__builtin_amdgcn_rsqf(d2), 1.0e6f); \
        if ((i) & 1) rs1 += w##i; else rs0 += w##i; }
    REP32(PASS1)
#undef PASS1
    float rs = rs0 + rs1;
    rs += __shfl_xor(rs, 1);
    rs += __shfl_xor(rs, 2);                   // all 4 lanes have full rowsum
    const float dinv = __builtin_amdgcn_rsqf(rs);
    if (q == 0)
        xs4_s[r] = make_float4(dinv * xa.x, dinv * xa.y, dinv * xa.z, dinv * xa.w);
    __syncthreads();

    // ---- pass 2: m = w_row . xs using cached weights (2 pk_fma/pair) ----
    v2 mA = {0.f, 0.f};
    v2 mB = {0.f, 0.f};
#define PASS2(i) { \
        float4 u = xs4_s[((i) << 2) | q]; \
        v2 wv2 = {w##i, w##i}; \
        mA = __builtin_elementwise_fma(wv2, (v2){u.x, u.y}, mA); \
        mB = __builtin_elementwise_fma(wv2, (v2){u.z, u.w}, mB); }
    REP32(PASS2)
#undef PASS2
    float m0 = mA.x, m1 = mA.y, m2 = mB.x, m3 = mB.y;
    m0 += __shfl_xor(m0, 1); m0 += __shfl_xor(m0, 2);
    m1 += __shfl_xor(m1, 1); m1 += __shfl_xor(m1, 2);
    m2 += __shfl_xor(m2, 1); m2 += __shfl_xor(m2, 2);
    m3 += __shfl_xor(m3, 1); m3 += __shfl_xor(m3, 2);
    if (q == 0)
        M4_s[r] = make_float4(dinv * m0, dinv * m1, dinv * m2, dinv * m3);
    __syncthreads();

    // ---- gates, transposed: thread <-> column j, 16 agents per wave ----
    {
        const int j  = t & 63;
        const int g  = t >> 6;                 // wave id 0..7 -> agent group
        const v2 W0 = {gw_s[j],       gw_s[256 + j]};
        const v2 W1 = {gw_s[64 + j],  gw_s[320 + j]};
        const v2 W2 = {gw_s[128 + j], gw_s[384 + j]};
        const v2 W3 = {gw_s[192 + j], gw_s[448 + j]};
        const v2 Bzh = {gb_s[j], gb_s[64 + j]};
        float acc = 0.f;
        #pragma unroll
        for (int i = 0; i < 16; ++i) {
            float4 mv = M4_s[g * 16 + i];      // wave-uniform broadcast
            v2 zh = __builtin_elementwise_fma((v2){mv.x, mv.x}, W0, Bzh);
            zh = __builtin_elementwise_fma((v2){mv.y, mv.y}, W1, zh);
            zh = __builtin_elementwise_fma((v2){mv.z, mv.z}, W2, zh);
            zh = __builtin_elementwise_fma((v2){mv.w, mv.w}, W3, zh);
            float ez = __builtin_amdgcn_exp2f(zh.x);
            float e2 = __builtin_amdgcn_exp2f(zh.y);
            // (1-sigmoid)*tanh = (e2-1) / ((1+ez)*(1+e2)), one rcp
            float num = e2 - 1.f;
            float den = (1.f + ez) * (1.f + e2);
            float hv  = num * __builtin_amdgcn_rcpf(den);
            acc += fmaxf(hv, 0.f);
        }
        red_s[g][j] = acc;
    }
    __syncthreads();

    if (t < 64) {
        float s = red_s[0][t] + red_s[1][t] + red_s[2][t] + red_s[3][t]
                + red_s[4][t] + red_s[5][t] + red_s[6][t] + red_s[7][t];
        part[(size_t)bl * 64 + t] = s;
    }
}

// ---------------------------------------------------------------------------
// Kernel 2: fused pool + decoder. One block of 1024 threads per batch.
// ---------------------------------------------------------------------------
__global__ __launch_bounds__(1024) void pooldec_kernel(
    const float* __restrict__ part,
    const float* __restrict__ D1_w, const float* __restrict__ D1_b,
    const float* __restrict__ D2_w, const float* __restrict__ D2_b,
    float* __restrict__ out)
{
    __shared__ float red_s[16][64];
    __shared__ float pooled_s[64];
    __shared__ float t1_s[256];
    const int t = threadIdx.x, b = blockIdx.x;

    // ---- pool over L: 16 groups x 16 rows ----
    {
        const int j = t & 63, g = t >> 6;
        const float* pb = part + ((size_t)b * L_ + g * 16) * 64;
        float s = 0.f;
        #pragma unroll
        for (int i = 0; i < 16; ++i) s += pb[i * 64 + j];
        red_s[g][j] = s;
    }
    __syncthreads();
    if (t < 64) {
        float s = 0.f;
        #pragma unroll
        for (int g = 0; g < 16; ++g) s += red_s[g][t];
        pooled_s[t] = s * (1.f / ((float)L_ * (float)A_));
    }
    __syncthreads();

    // ---- D1: 256 outputs, 4 threads per output (16 h each) ----
    {
        const int o = t >> 2, sub = t & 3;
        float acc = 0.f;
        #pragma unroll
        for (int hh = 0; hh < 16; ++hh) {
            int h = sub * 16 + hh;
            acc += pooled_s[h] * D1_w[h * 256 + o];
        }
        acc += __shfl_xor(acc, 1);
        acc += __shfl_xor(acc, 2);
        if (sub == 0) t1_s[o] = fmaxf(acc + D1_b[o], 0.f);
    }
    __syncthreads();

    // ---- D2: 512 outputs, 2 threads per output (128 k each) ----
    {
        const int o = t >> 1, kh = t & 1;
        float acc = 0.f;
        for (int kk = 0; kk < 128; ++kk) {
            int k = kh * 128 + kk;
            acc += t1_s[k] * D2_w[k * 512 + o];
        }
        acc += __shfl_xor(acc, 1);
        if (kh == 0) out[(size_t)b * 512 + o] = acc + D2_b[o];
    }
}

// ---------------------------------------------------------------------------
extern "C" void kernel_launch(void* const* d_in, const int* in_sizes, int n_in,
                              void* d_out, int out_size, void* d_ws, size_t ws_size,
                              hipStream_t stream)
{
    const float* x    = (const float*)d_in[0];
    // d_in[1..3]: x_mark_enc, x_dec, x_mark_dec — unused by the reference
    const float* W_z  = (const float*)d_in[4];
    const float* b_z  = (const float*)d_in[5];
    // d_in[6], d_in[7]: W_r, b_r — dead code in the reference
    const float* W_h  = (const float*)d_in[8];
    const float* b_h  = (const float*)d_in[9];
    const float* Lz_w = (const float*)d_in[10];
    const float* Lz_b = (const float*)d_in[11];
    // d_in[12], d_in[13]: Lr_w, Lr_b — dead
    const float* Lh_w = (const float*)d_in[14];
    const float* Lh_b = (const float*)d_in[15];
    const float* D1_w = (const float*)d_in[16];
    const float* D1_b = (const float*)d_in[17];
    const float* D2_w = (const float*)d_in[18];
    const float* D2_b = (const float*)d_in[19];

    float* ws  = (float*)d_ws;
    float* out = (float*)d_out;

    precomp_kernel<<<5, 128, 0, stream>>>(W_z, b_z, W_h, b_h,
                                          Lz_w, Lz_b, Lh_w, Lh_b, ws);
    tgcn_kernel<<<B_ * L_, 512, 0, stream>>>(x, ws, ws + WS_PART);
    pooldec_kernel<<<B_, 1024, 0, stream>>>(ws + WS_PART, D1_w, D1_b,
                                            D2_w, D2_b, out);
}